// Round 4
// baseline (432.189 us; speedup 1.0000x reference)
//
#include <hip/hip_runtime.h>
#include <hip/hip_bf16.h>
#include <math.h>

namespace {
constexpr int kH = 384, kW = 384, kBn = 2;
constexpr int kHW = kH * kW;       // 147456
constexpr int kOMD = 112;
constexpr int kNB = kBn * (kHW / 64);   // 4608 blocks
constexpr int kNB8 = kNB / 8;           // 576 per XCD
// d_ws layout (bytes): value bf16 [2][4][kHW][16], then bf16 weights
constexpr size_t kOffWvh = 37748736;            // ushort Wvt_hi [64][64]
constexpr size_t kOffWvl = kOffWvh + 8192;      // ushort Wvt_lo [64][64]
constexpr size_t kOffWom = kOffWvl + 8192;      // ushort Womt  [112][64]
constexpr size_t kOffWot = kOffWom + 14336;     // ushort Wot   [64][64]
}

typedef __attribute__((ext_vector_type(8))) short short8;
typedef __attribute__((ext_vector_type(4))) float f32x4;

__device__ __forceinline__ int swz(int bid) {
    return (bid & 7) * kNB8 + (bid >> 3);   // XCD-aware contiguous ranges
}

__device__ __forceinline__ float bl(unsigned u) { return __uint_as_float(u << 16); }
__device__ __forceinline__ float bh(unsigned u) { return __uint_as_float(u & 0xffff0000u); }
__device__ __forceinline__ unsigned short f2bf(float f) {
    union { __hip_bfloat16 b; unsigned short s; } u;
    u.b = __float2bfloat16(f);   // RNE
    return u.s;
}
__device__ __forceinline__ float bf2f(unsigned short s) {
    return __uint_as_float((unsigned)s << 16);
}

// ---- prep: transpose+cast weights to bf16 (hi/lo split for Wv) ----
__global__ __launch_bounds__(256) void k_prep(
        const float* __restrict__ Wv, const float* __restrict__ Wom,
        const float* __restrict__ Wo, unsigned short* __restrict__ wsu) {
    unsigned short* Wvh = wsu + kOffWvh / 2;
    unsigned short* Wvl = wsu + kOffWvl / 2;
    unsigned short* Wmt = wsu + kOffWom / 2;
    unsigned short* Wot = wsu + kOffWot / 2;
    const int tid = blockIdx.x * 256 + threadIdx.x;
    if (tid < 4096) {
        const int co = tid >> 6, ci = tid & 63;
        const float v = Wv[ci * 64 + co];
        const unsigned short h = f2bf(v);
        Wvh[co * 64 + ci] = h;
        Wvl[co * 64 + ci] = f2bf(v - bf2f(h));
    } else if (tid < 4096 + 7168) {
        const int i = tid - 4096;
        const int om = i >> 6, ci = i & 63;
        Wmt[om * 64 + ci] = f2bf(Wom[ci * kOMD + om]);
    } else if (tid < 4096 + 7168 + 4096) {
        const int i = tid - 4096 - 7168;
        const int co = i >> 6, ci = i & 63;
        Wot[co * 64 + ci] = f2bf(Wo[ci * 64 + co]);
    }
}

// ---- K1: value (MFMA, hi/lo split ~= fp32 accuracy), bf16 out ----
__global__ __launch_bounds__(256) void k_value(
        const float* __restrict__ inp, const float* __restrict__ bv,
        const unsigned short* __restrict__ Wvh, const unsigned short* __restrict__ Wvl,
        unsigned short* __restrict__ value) {
    __shared__ __align__(16) char smem[18432];
    unsigned short* xh = (unsigned short*)smem;          // [64][72] bf16 hi
    unsigned short* xl = xh + 64 * 72;                   // [64][72] bf16 lo
    float* vb = (float*)smem;                            // [64][69] f32 (reused)

    const int tid = threadIdx.x;
    const int bid = swz(blockIdx.x);
    const int b = bid / (kHW / 64);
    const int pix0 = (bid % (kHW / 64)) * 64;
    const float* ib = inp + (size_t)b * 64 * kHW + pix0;

    // staging: transpose + split-cast. thread -> (pixel p, ci pair)
    #pragma unroll
    for (int j = 0; j < 8; ++j) {
        const int i = tid + j * 256;
        const int c2 = i >> 6, p = i & 63;
        const int c = c2 * 2;
        const float v0 = ib[(size_t)c * kHW + p];
        const float v1 = ib[(size_t)(c + 1) * kHW + p];
        const unsigned short h0 = f2bf(v0), h1 = f2bf(v1);
        const unsigned short l0 = f2bf(v0 - bf2f(h0));
        const unsigned short l1 = f2bf(v1 - bf2f(h1));
        *(unsigned*)&xh[p * 72 + c] = (unsigned)h0 | ((unsigned)h1 << 16);
        *(unsigned*)&xl[p * 72 + c] = (unsigned)l0 | ((unsigned)l1 << 16);
    }
    __syncthreads();

    const int lane = tid & 63, wid = tid >> 6;
    const int m = lane & 15, quad = lane >> 4;
    const int row = wid * 16 + m;
    const short8 ah0 = *(const short8*)&xh[row * 72 + quad * 8];
    const short8 ah1 = *(const short8*)&xh[row * 72 + 32 + quad * 8];
    const short8 al0 = *(const short8*)&xl[row * 72 + quad * 8];
    const short8 al1 = *(const short8*)&xl[row * 72 + 32 + quad * 8];
    f32x4 accs[4];
    #pragma unroll
    for (int nt = 0; nt < 4; ++nt) {
        const int ncol = nt * 16 + m;
        const short8 b0 = *(const short8*)&Wvh[ncol * 64 + quad * 8];
        const short8 b1 = *(const short8*)&Wvh[ncol * 64 + 32 + quad * 8];
        const short8 c0 = *(const short8*)&Wvl[ncol * 64 + quad * 8];
        const short8 c1 = *(const short8*)&Wvl[ncol * 64 + 32 + quad * 8];
        f32x4 acc = {0.f, 0.f, 0.f, 0.f};
        acc = __builtin_amdgcn_mfma_f32_16x16x32_bf16(ah0, b0, acc, 0, 0, 0);
        acc = __builtin_amdgcn_mfma_f32_16x16x32_bf16(ah1, b1, acc, 0, 0, 0);
        acc = __builtin_amdgcn_mfma_f32_16x16x32_bf16(al0, b0, acc, 0, 0, 0);
        acc = __builtin_amdgcn_mfma_f32_16x16x32_bf16(al1, b1, acc, 0, 0, 0);
        acc = __builtin_amdgcn_mfma_f32_16x16x32_bf16(ah0, c0, acc, 0, 0, 0);
        acc = __builtin_amdgcn_mfma_f32_16x16x32_bf16(ah1, c1, acc, 0, 0, 0);
        accs[nt] = acc;
    }
    __syncthreads();   // xh/xl dead; reuse as vb
    #pragma unroll
    for (int nt = 0; nt < 4; ++nt) {
        const int co = nt * 16 + m;
        const float bvn = bv[co];
        #pragma unroll
        for (int r = 0; r < 4; ++r) {
            const int px = wid * 16 + quad * 4 + r;
            vb[px * 69 + co] = accs[nt][r] + bvn;
        }
    }
    __syncthreads();
    // repack: thread (p,g) -> 32B coalesced bf16 store
    {
        const int p = tid & 63, g = tid >> 6;
        unsigned pk[8];
        #pragma unroll
        for (int j = 0; j < 8; ++j) {
            const float e0 = vb[p * 69 + g * 16 + 2 * j];
            const float e1 = vb[p * 69 + g * 16 + 2 * j + 1];
            pk[j] = (unsigned)f2bf(e0) | ((unsigned)f2bf(e1) << 16);
        }
        unsigned short* vo = value + ((size_t)(b * 4 + g) * kHW + pix0 + p) * 16;
        *(uint4*)vo = make_uint4(pk[0], pk[1], pk[2], pk[3]);
        *((uint4*)vo + 1) = make_uint4(pk[4], pk[5], pk[6], pk[7]);
    }
}

// ---- K2: depthwise -> om (MFMA) -> sampling -> @Wo (MFMA) -> out ----
__global__ __launch_bounds__(256) void k_main(
        const float* __restrict__ inp, const float* __restrict__ Wdw,
        const float* __restrict__ bdw, const float* __restrict__ bom,
        const unsigned short* __restrict__ Womt, const unsigned short* __restrict__ Wot,
        const unsigned short* __restrict__ value, float* __restrict__ out) {
    __shared__ __align__(16) unsigned short dwb[64 * 72];  // bf16 [px][ci]; reused for sampled
    __shared__ float omL[64 * 113];                        // f32 [px][omidx]

    const int tid = threadIdx.x;
    const int bid = swz(blockIdx.x);
    const int b = bid / (kH * (kW / 64));
    const int rem = bid % (kH * (kW / 64));
    const int h = rem / (kW / 64);
    const int w0 = (rem % (kW / 64)) * 64;

    const int p = tid & 63;
    const int gs = __builtin_amdgcn_readfirstlane(tid >> 6);
    const int m = p & 15, quad = p >> 4;

    // ---- stage A: depthwise 3x3 (zero pad) -> dwb bf16 [p][gs*16..] ----
    {
        const int w = w0 + p;
        float dwv[16];
        #pragma unroll 4
        for (int cc = 0; cc < 16; ++cc) {
            const int c = gs * 16 + cc;
            const float* ibc = inp + (size_t)(b * 64 + c) * kHW;
            float s = bdw[c];
            #pragma unroll
            for (int r = 0; r < 3; ++r) {
                const int y = h - 1 + r;
                if (y >= 0 && y < kH) {
                    const float* rowp = ibc + (size_t)y * kW;
                    #pragma unroll
                    for (int kx = 0; kx < 3; ++kx) {
                        const int x = w - 1 + kx;
                        const float v = (x >= 0 && x < kW) ? rowp[x] : 0.f;
                        s = fmaf(v, Wdw[c * 9 + r * 3 + kx], s);
                    }
                }
            }
            dwv[cc] = s;
        }
        unsigned pk[8];
        #pragma unroll
        for (int j = 0; j < 8; ++j)
            pk[j] = (unsigned)f2bf(dwv[2 * j]) | ((unsigned)f2bf(dwv[2 * j + 1]) << 16);
        unsigned short* dst = &dwb[p * 72 + gs * 16];
        *(uint4*)dst = make_uint4(pk[0], pk[1], pk[2], pk[3]);
        *((uint4*)dst + 1) = make_uint4(pk[4], pk[5], pk[6], pk[7]);
    }
    __syncthreads();

    // ---- stage B: om = dw @ Wom + bom via MFMA; wave gs -> px band gs*16.. ----
    {
        const int row = gs * 16 + m;
        const short8 a0 = *(const short8*)&dwb[row * 72 + quad * 8];
        const short8 a1 = *(const short8*)&dwb[row * 72 + 32 + quad * 8];
        #pragma unroll
        for (int nt = 0; nt < 7; ++nt) {
            const int ncol = nt * 16 + m;
            const short8 b0 = *(const short8*)&Womt[ncol * 64 + quad * 8];
            const short8 b1 = *(const short8*)&Womt[ncol * 64 + 32 + quad * 8];
            const float bias = bom[ncol];
            f32x4 acc = {bias, bias, bias, bias};
            acc = __builtin_amdgcn_mfma_f32_16x16x32_bf16(a0, b0, acc, 0, 0, 0);
            acc = __builtin_amdgcn_mfma_f32_16x16x32_bf16(a1, b1, acc, 0, 0, 0);
            #pragma unroll
            for (int r = 0; r < 4; ++r)
                omL[(gs * 16 + quad * 4 + r) * 113 + ncol] = acc[r];
        }
    }
    __syncthreads();   // omL ready; dwb reads done (safe to overwrite below)

    // ---- stage C: deformable bilinear sampling (bf16 value gathers) ----
    {
        float om[27];
        #pragma unroll
        for (int j = 0; j < 27; ++j) om[j] = omL[p * 113 + gs * 27 + j];
        float acc[16];
        #pragma unroll
        for (int j = 0; j < 16; ++j) acc[j] = 0.f;
        const float fw = (float)(w0 + p);
        const float fh = (float)h;
        const unsigned short* vbase = value + (size_t)(b * 4 + gs) * kHW * 16;
        #pragma unroll
        for (int k = 0; k < 9; ++k) {
            const int ky = k / 3, kx = k % 3;
            const float dx = om[2 * k];
            const float dy = om[2 * k + 1];
            const float mk = om[18 + k];
            const float px = fw + (float)(kx - 1) + dx;
            const float py = fh + (float)(ky - 1) + dy;
            const float x0f = floorf(px), y0f = floorf(py);
            const int x0 = (int)x0f, y0 = (int)y0f;
            const float wx1 = px - x0f, wy1 = py - y0f;
            const float wx0 = 1.f - wx1, wy0 = 1.f - wy1;
            #pragma unroll
            for (int cor = 0; cor < 4; ++cor) {
                const int dy2 = cor >> 1, dx2 = cor & 1;
                const int xi = x0 + dx2, yi = y0 + dy2;
                float wgt = (dy2 ? wy1 : wy0) * (dx2 ? wx1 : wx0) * mk;
                if (xi < 0 || xi >= kW || yi < 0 || yi >= kH) wgt = 0.f;
                const int xc = min(max(xi, 0), kW - 1);
                const int yc = min(max(yi, 0), kH - 1);
                const uint4* vp = (const uint4*)(vbase + ((size_t)yc * kW + xc) * 16);
                const uint4 u0 = vp[0];
                const uint4 u1 = vp[1];
                acc[0]  = fmaf(wgt, bl(u0.x), acc[0]);
                acc[1]  = fmaf(wgt, bh(u0.x), acc[1]);
                acc[2]  = fmaf(wgt, bl(u0.y), acc[2]);
                acc[3]  = fmaf(wgt, bh(u0.y), acc[3]);
                acc[4]  = fmaf(wgt, bl(u0.z), acc[4]);
                acc[5]  = fmaf(wgt, bh(u0.z), acc[5]);
                acc[6]  = fmaf(wgt, bl(u0.w), acc[6]);
                acc[7]  = fmaf(wgt, bh(u0.w), acc[7]);
                acc[8]  = fmaf(wgt, bl(u1.x), acc[8]);
                acc[9]  = fmaf(wgt, bh(u1.x), acc[9]);
                acc[10] = fmaf(wgt, bl(u1.y), acc[10]);
                acc[11] = fmaf(wgt, bh(u1.y), acc[11]);
                acc[12] = fmaf(wgt, bl(u1.z), acc[12]);
                acc[13] = fmaf(wgt, bh(u1.z), acc[13]);
                acc[14] = fmaf(wgt, bl(u1.w), acc[14]);
                acc[15] = fmaf(wgt, bh(u1.w), acc[15]);
            }
        }
        // pack sampled -> bf16 into dwb [px][ch] (dw dead; barrier above done)
        unsigned pk[8];
        #pragma unroll
        for (int j = 0; j < 8; ++j)
            pk[j] = (unsigned)f2bf(acc[2 * j]) | ((unsigned)f2bf(acc[2 * j + 1]) << 16);
        unsigned short* dst = &dwb[p * 72 + gs * 16];
        *(uint4*)dst = make_uint4(pk[0], pk[1], pk[2], pk[3]);
        *((uint4*)dst + 1) = make_uint4(pk[4], pk[5], pk[6], pk[7]);
    }
    __syncthreads();

    // ---- stage D: out = sampled @ Wo via MFMA; coalesced float4 stores ----
    {
        const int row = gs * 16 + m;
        const short8 a0 = *(const short8*)&dwb[row * 72 + quad * 8];
        const short8 a1 = *(const short8*)&dwb[row * 72 + 32 + quad * 8];
        #pragma unroll
        for (int nt = 0; nt < 4; ++nt) {
            const int ncol = nt * 16 + m;
            const short8 b0 = *(const short8*)&Wot[ncol * 64 + quad * 8];
            const short8 b1 = *(const short8*)&Wot[ncol * 64 + 32 + quad * 8];
            f32x4 acc = {0.f, 0.f, 0.f, 0.f};
            acc = __builtin_amdgcn_mfma_f32_16x16x32_bf16(a0, b0, acc, 0, 0, 0);
            acc = __builtin_amdgcn_mfma_f32_16x16x32_bf16(a1, b1, acc, 0, 0, 0);
            float4 st = make_float4(acc[0], acc[1], acc[2], acc[3]);
            *(float4*)&out[(size_t)(b * 64 + ncol) * kHW + (size_t)h * kW +
                           w0 + gs * 16 + quad * 4] = st;
        }
    }
}

extern "C" void kernel_launch(void* const* d_in, const int* in_sizes, int n_in,
                              void* d_out, int out_size, void* d_ws, size_t ws_size,
                              hipStream_t stream) {
    const float* inp = (const float*)d_in[0];
    const float* Wv  = (const float*)d_in[1];
    const float* bv  = (const float*)d_in[2];
    const float* Wdw = (const float*)d_in[3];
    const float* bdw = (const float*)d_in[4];
    const float* Wom = (const float*)d_in[5];
    const float* bom = (const float*)d_in[6];
    const float* Wo  = (const float*)d_in[7];
    float* outp = (float*)d_out;
    unsigned short* wsu = (unsigned short*)d_ws;
    unsigned short* value = wsu;                      // [b][g][yx][16] bf16
    const unsigned short* Wvh = wsu + kOffWvh / 2;
    const unsigned short* Wvl = wsu + kOffWvl / 2;
    const unsigned short* Wmt = wsu + kOffWom / 2;
    const unsigned short* Wot = wsu + kOffWot / 2;

    k_prep<<<60, 256, 0, stream>>>(Wv, Wom, Wo, wsu);
    k_value<<<kNB, 256, 0, stream>>>(inp, bv, Wvh, Wvl, value);
    k_main<<<kNB, 256, 0, stream>>>(inp, Wdw, bdw, bom, Wmt, Wot, value, outp);
}

// Round 5
// 377.204 us; speedup vs baseline: 1.1458x; 1.1458x over previous
//
#include <hip/hip_runtime.h>
#include <hip/hip_bf16.h>
#include <math.h>

namespace {
constexpr int kH = 384, kW = 384, kBn = 2;
constexpr int kHW = kH * kW;       // 147456
constexpr int kOMD = 112;
constexpr int kNBv = kBn * (kHW / 64);  // 4608 row-blocks for k_value
constexpr int kNBv8 = kNBv / 8;
constexpr int kNT = kBn * 48 * 48;      // 4608 8x8 tiles for k_main
constexpr int kNT8 = kNT / 8;
// d_ws layout (bytes): value bf16 [2][4][kHW][16], then bf16 weights
constexpr size_t kOffWvh = 37748736;            // ushort Wvt_hi [64][64]
constexpr size_t kOffWvl = kOffWvh + 8192;      // ushort Wvt_lo [64][64]
constexpr size_t kOffWom = kOffWvl + 8192;      // ushort Womt  [112][64]
constexpr size_t kOffWot = kOffWom + 14336;     // ushort Wot   [64][64]
// sampling window: 12x12 positions, row stride 13 units, group stride 156
constexpr int kWR = 12, kWS = 13, kWGS = 156;   // units of 16 ushorts (32B)
}

typedef __attribute__((ext_vector_type(8))) short short8;
typedef __attribute__((ext_vector_type(4))) float f32x4;

__device__ __forceinline__ int swzV(int bid) { return (bid & 7) * kNBv8 + (bid >> 3); }
__device__ __forceinline__ int swzT(int bid) { return (bid & 7) * kNT8 + (bid >> 3); }

__device__ __forceinline__ float bl(unsigned u) { return __uint_as_float(u << 16); }
__device__ __forceinline__ float bh(unsigned u) { return __uint_as_float(u & 0xffff0000u); }
__device__ __forceinline__ unsigned short f2bf(float f) {
    union { __hip_bfloat16 b; unsigned short s; } u;
    u.b = __float2bfloat16(f);   // RNE
    return u.s;
}
__device__ __forceinline__ float bf2f(unsigned short s) {
    return __uint_as_float((unsigned)s << 16);
}

// ---- prep: transpose+cast weights to bf16 (hi/lo split for Wv) ----
__global__ __launch_bounds__(256) void k_prep(
        const float* __restrict__ Wv, const float* __restrict__ Wom,
        const float* __restrict__ Wo, unsigned short* __restrict__ wsu) {
    unsigned short* Wvh = wsu + kOffWvh / 2;
    unsigned short* Wvl = wsu + kOffWvl / 2;
    unsigned short* Wmt = wsu + kOffWom / 2;
    unsigned short* Wot = wsu + kOffWot / 2;
    const int tid = blockIdx.x * 256 + threadIdx.x;
    if (tid < 4096) {
        const int co = tid >> 6, ci = tid & 63;
        const float v = Wv[ci * 64 + co];
        const unsigned short h = f2bf(v);
        Wvh[co * 64 + ci] = h;
        Wvl[co * 64 + ci] = f2bf(v - bf2f(h));
    } else if (tid < 4096 + 7168) {
        const int i = tid - 4096;
        const int om = i >> 6, ci = i & 63;
        Wmt[om * 64 + ci] = f2bf(Wom[ci * kOMD + om]);
    } else if (tid < 4096 + 7168 + 4096) {
        const int i = tid - 4096 - 7168;
        const int co = i >> 6, ci = i & 63;
        Wot[co * 64 + ci] = f2bf(Wo[ci * 64 + co]);
    }
}

// ---- K1: value (MFMA, hi/lo split ~= fp32 accuracy), bf16 out ----
__global__ __launch_bounds__(256) void k_value(
        const float* __restrict__ inp, const float* __restrict__ bv,
        const unsigned short* __restrict__ Wvh, const unsigned short* __restrict__ Wvl,
        unsigned short* __restrict__ value) {
    __shared__ __align__(16) char smem[18432];
    unsigned short* xh = (unsigned short*)smem;          // [64][72] bf16 hi
    unsigned short* xl = xh + 64 * 72;                   // [64][72] bf16 lo
    float* vb = (float*)smem;                            // [64][69] f32 (reused)

    const int tid = threadIdx.x;
    const int bid = swzV(blockIdx.x);
    const int b = bid / (kHW / 64);
    const int pix0 = (bid % (kHW / 64)) * 64;
    const float* ib = inp + (size_t)b * 64 * kHW + pix0;

    #pragma unroll
    for (int j = 0; j < 8; ++j) {
        const int i = tid + j * 256;
        const int c2 = i >> 6, p = i & 63;
        const int c = c2 * 2;
        const float v0 = ib[(size_t)c * kHW + p];
        const float v1 = ib[(size_t)(c + 1) * kHW + p];
        const unsigned short h0 = f2bf(v0), h1 = f2bf(v1);
        const unsigned short l0 = f2bf(v0 - bf2f(h0));
        const unsigned short l1 = f2bf(v1 - bf2f(h1));
        *(unsigned*)&xh[p * 72 + c] = (unsigned)h0 | ((unsigned)h1 << 16);
        *(unsigned*)&xl[p * 72 + c] = (unsigned)l0 | ((unsigned)l1 << 16);
    }
    __syncthreads();

    const int lane = tid & 63, wid = tid >> 6;
    const int m = lane & 15, quad = lane >> 4;
    const int row = wid * 16 + m;
    const short8 ah0 = *(const short8*)&xh[row * 72 + quad * 8];
    const short8 ah1 = *(const short8*)&xh[row * 72 + 32 + quad * 8];
    const short8 al0 = *(const short8*)&xl[row * 72 + quad * 8];
    const short8 al1 = *(const short8*)&xl[row * 72 + 32 + quad * 8];
    f32x4 accs[4];
    #pragma unroll
    for (int nt = 0; nt < 4; ++nt) {
        const int ncol = nt * 16 + m;
        const short8 b0 = *(const short8*)&Wvh[ncol * 64 + quad * 8];
        const short8 b1 = *(const short8*)&Wvh[ncol * 64 + 32 + quad * 8];
        const short8 c0 = *(const short8*)&Wvl[ncol * 64 + quad * 8];
        const short8 c1 = *(const short8*)&Wvl[ncol * 64 + 32 + quad * 8];
        f32x4 acc = {0.f, 0.f, 0.f, 0.f};
        acc = __builtin_amdgcn_mfma_f32_16x16x32_bf16(ah0, b0, acc, 0, 0, 0);
        acc = __builtin_amdgcn_mfma_f32_16x16x32_bf16(ah1, b1, acc, 0, 0, 0);
        acc = __builtin_amdgcn_mfma_f32_16x16x32_bf16(al0, b0, acc, 0, 0, 0);
        acc = __builtin_amdgcn_mfma_f32_16x16x32_bf16(al1, b1, acc, 0, 0, 0);
        acc = __builtin_amdgcn_mfma_f32_16x16x32_bf16(ah0, c0, acc, 0, 0, 0);
        acc = __builtin_amdgcn_mfma_f32_16x16x32_bf16(ah1, c1, acc, 0, 0, 0);
        accs[nt] = acc;
    }
    __syncthreads();   // xh/xl dead; reuse as vb
    #pragma unroll
    for (int nt = 0; nt < 4; ++nt) {
        const int co = nt * 16 + m;
        const float bvn = bv[co];
        #pragma unroll
        for (int r = 0; r < 4; ++r) {
            const int px = wid * 16 + quad * 4 + r;
            vb[px * 69 + co] = accs[nt][r] + bvn;
        }
    }
    __syncthreads();
    {
        const int p = tid & 63, g = tid >> 6;
        unsigned pk[8];
        #pragma unroll
        for (int j = 0; j < 8; ++j) {
            const float e0 = vb[p * 69 + g * 16 + 2 * j];
            const float e1 = vb[p * 69 + g * 16 + 2 * j + 1];
            pk[j] = (unsigned)f2bf(e0) | ((unsigned)f2bf(e1) << 16);
        }
        unsigned short* vo = value + ((size_t)(b * 4 + g) * kHW + pix0 + p) * 16;
        *(uint4*)vo = make_uint4(pk[0], pk[1], pk[2], pk[3]);
        *((uint4*)vo + 1) = make_uint4(pk[4], pk[5], pk[6], pk[7]);
    }
}

// ---- K2: 8x8 tile: depthwise -> om(MFMA) -> LDS-window sampling -> @Wo(MFMA) ----
__global__ __launch_bounds__(256) void k_main(
        const float* __restrict__ inp, const float* __restrict__ Wdw,
        const float* __restrict__ bdw, const float* __restrict__ bom,
        const unsigned short* __restrict__ Womt, const unsigned short* __restrict__ Wot,
        const unsigned short* __restrict__ value, float* __restrict__ out) {
    __shared__ __align__(16) unsigned short dwb[64 * 72];    // bf16 [px][ci]; reused for sampled
    __shared__ __align__(16) unsigned short omB[64 * 122];   // bf16 [px][om]
    __shared__ __align__(16) unsigned short win[4 * kWGS * 16]; // value window [g][dy(13)][dx][16]

    const int tid = threadIdx.x;
    const int bid = swzT(blockIdx.x);
    const int b = bid / (48 * 48);
    const int rem = bid % (48 * 48);
    const int tyi = rem / 48;
    const int txi = rem % 48;
    const int ty0 = tyi * 8, tx0 = txi * 8;

    const int p = tid & 63;
    const int gs = __builtin_amdgcn_readfirstlane(tid >> 6);
    const int m = p & 15, quad = p >> 4;

    // ---- stage A: depthwise 3x3 (zero pad), per-lane pixel of the 8x8 tile ----
    {
        const int w = tx0 + (p & 7);
        const int hh = ty0 + (p >> 3);
        float dwv[16];
        #pragma unroll 4
        for (int cc = 0; cc < 16; ++cc) {
            const int c = gs * 16 + cc;
            const float* ibc = inp + (size_t)(b * 64 + c) * kHW;
            float s = bdw[c];
            #pragma unroll
            for (int r = 0; r < 3; ++r) {
                const int y = hh - 1 + r;
                if (y >= 0 && y < kH) {
                    const float* rowp = ibc + (size_t)y * kW;
                    #pragma unroll
                    for (int kx2 = 0; kx2 < 3; ++kx2) {
                        const int x = w - 1 + kx2;
                        const float v = (x >= 0 && x < kW) ? rowp[x] : 0.f;
                        s = fmaf(v, Wdw[c * 9 + r * 3 + kx2], s);
                    }
                }
            }
            dwv[cc] = s;
        }
        unsigned pk[8];
        #pragma unroll
        for (int j = 0; j < 8; ++j)
            pk[j] = (unsigned)f2bf(dwv[2 * j]) | ((unsigned)f2bf(dwv[2 * j + 1]) << 16);
        unsigned short* dst = &dwb[p * 72 + gs * 16];
        *(uint4*)dst = make_uint4(pk[0], pk[1], pk[2], pk[3]);
        *((uint4*)dst + 1) = make_uint4(pk[4], pk[5], pk[6], pk[7]);
    }

    // ---- window staging: value rows ty0-2..+9, cols tx0-2..+9, all 4 groups ----
    for (int i = tid; i < 4 * kWR * kWR * 2; i += 256) {   // 1152 half-units of 16B
        const int unit = i >> 1, half = i & 1;
        const int g = unit / (kWR * kWR);
        const int r2 = unit - g * (kWR * kWR);
        const int dy = r2 / kWR;
        const int dx = r2 - dy * kWR;
        const int gy = min(max(ty0 - 2 + dy, 0), kH - 1);
        const int gx = min(max(tx0 - 2 + dx, 0), kW - 1);
        const uint4 v = *(const uint4*)(value +
                ((size_t)(b * 4 + g) * kHW + (size_t)gy * kW + gx) * 16 + half * 8);
        *(uint4*)&win[(g * kWGS + dy * kWS + dx) * 16 + half * 8] = v;
    }
    __syncthreads();

    // ---- stage B: om = dw @ Wom + bom via MFMA -> omB bf16 ----
    {
        const int row = gs * 16 + m;
        const short8 a0 = *(const short8*)&dwb[row * 72 + quad * 8];
        const short8 a1 = *(const short8*)&dwb[row * 72 + 32 + quad * 8];
        #pragma unroll
        for (int nt = 0; nt < 7; ++nt) {
            const int ncol = nt * 16 + m;
            const short8 b0 = *(const short8*)&Womt[ncol * 64 + quad * 8];
            const short8 b1 = *(const short8*)&Womt[ncol * 64 + 32 + quad * 8];
            const float bias = bom[ncol];
            f32x4 acc = {bias, bias, bias, bias};
            acc = __builtin_amdgcn_mfma_f32_16x16x32_bf16(a0, b0, acc, 0, 0, 0);
            acc = __builtin_amdgcn_mfma_f32_16x16x32_bf16(a1, b1, acc, 0, 0, 0);
            #pragma unroll
            for (int r = 0; r < 4; ++r)
                omB[(gs * 16 + quad * 4 + r) * 122 + ncol] = f2bf(acc[r]);
        }
    }
    __syncthreads();

    // ---- stage C: deformable bilinear sampling from the LDS window ----
    {
        float acc[16];
        #pragma unroll
        for (int j = 0; j < 16; ++j) acc[j] = 0.f;
        const int xo = p & 7, yo = p >> 3;
        const float fw = (float)(tx0 + xo);
        const float fh = (float)(ty0 + yo);
        const unsigned short* vbase = value + (size_t)(b * 4 + gs) * kHW * 16;
        const unsigned short* omr = &omB[p * 122 + gs * 27];
        #pragma unroll 1
        for (int k = 0; k < 9; ++k) {
            const int ky = k / 3, kx = k % 3;
            const float dx = bf2f(omr[2 * k]);
            const float dy = bf2f(omr[2 * k + 1]);
            const float mk = bf2f(omr[18 + k]);
            const float px = fw + (float)(kx - 1) + dx;
            const float py = fh + (float)(ky - 1) + dy;
            const float x0f = floorf(px), y0f = floorf(py);
            const int x0 = (int)x0f, y0 = (int)y0f;
            const float wx1 = px - x0f, wy1 = py - y0f;
            const float wx0 = 1.f - wx1, wy0 = 1.f - wy1;
            #pragma unroll
            for (int cor = 0; cor < 4; ++cor) {
                const int dy2 = cor >> 1, dx2 = cor & 1;
                const int xi = x0 + dx2, yi = y0 + dy2;
                const bool inimg = (xi >= 0) & (xi < kW) & (yi >= 0) & (yi < kH);
                float wgt = (dy2 ? wy1 : wy0) * (dx2 ? wx1 : wx0) * mk;
                if (!inimg) wgt = 0.f;
                const int ly = yi - (ty0 - 2), lx = xi - (tx0 - 2);
                const bool inwin = ((unsigned)ly < (unsigned)kWR) &
                                   ((unsigned)lx < (unsigned)kWR);
                const int lyc = min(max(ly, 0), kWR - 1);
                const int lxc = min(max(lx, 0), kWR - 1);
                const uint4* wp = (const uint4*)&win[(gs * kWGS + lyc * kWS + lxc) * 16];
                uint4 u0 = wp[0];
                uint4 u1 = wp[1];
                if (__builtin_expect(inimg & !inwin, 0)) {   // rare: big offset
                    const uint4* vp = (const uint4*)(vbase + ((size_t)yi * kW + xi) * 16);
                    u0 = vp[0];
                    u1 = vp[1];
                }
                acc[0]  = fmaf(wgt, bl(u0.x), acc[0]);
                acc[1]  = fmaf(wgt, bh(u0.x), acc[1]);
                acc[2]  = fmaf(wgt, bl(u0.y), acc[2]);
                acc[3]  = fmaf(wgt, bh(u0.y), acc[3]);
                acc[4]  = fmaf(wgt, bl(u0.z), acc[4]);
                acc[5]  = fmaf(wgt, bh(u0.z), acc[5]);
                acc[6]  = fmaf(wgt, bl(u0.w), acc[6]);
                acc[7]  = fmaf(wgt, bh(u0.w), acc[7]);
                acc[8]  = fmaf(wgt, bl(u1.x), acc[8]);
                acc[9]  = fmaf(wgt, bh(u1.x), acc[9]);
                acc[10] = fmaf(wgt, bl(u1.y), acc[10]);
                acc[11] = fmaf(wgt, bh(u1.y), acc[11]);
                acc[12] = fmaf(wgt, bl(u1.z), acc[12]);
                acc[13] = fmaf(wgt, bh(u1.z), acc[13]);
                acc[14] = fmaf(wgt, bl(u1.w), acc[14]);
                acc[15] = fmaf(wgt, bh(u1.w), acc[15]);
            }
        }
        unsigned pk[8];
        #pragma unroll
        for (int j = 0; j < 8; ++j)
            pk[j] = (unsigned)f2bf(acc[2 * j]) | ((unsigned)f2bf(acc[2 * j + 1]) << 16);
        unsigned short* dst = &dwb[p * 72 + gs * 16];
        *(uint4*)dst = make_uint4(pk[0], pk[1], pk[2], pk[3]);
        *((uint4*)dst + 1) = make_uint4(pk[4], pk[5], pk[6], pk[7]);
    }
    __syncthreads();

    // ---- stage D: out = sampled @ Wo via MFMA; float4 stores ----
    {
        const int row = gs * 16 + m;
        const short8 a0 = *(const short8*)&dwb[row * 72 + quad * 8];
        const short8 a1 = *(const short8*)&dwb[row * 72 + 32 + quad * 8];
        const int pxq = gs * 16 + quad * 4;
        const int yq = pxq >> 3, xq = pxq & 7;
        #pragma unroll
        for (int nt = 0; nt < 4; ++nt) {
            const int ncol = nt * 16 + m;
            const short8 b0 = *(const short8*)&Wot[ncol * 64 + quad * 8];
            const short8 b1 = *(const short8*)&Wot[ncol * 64 + 32 + quad * 8];
            f32x4 acc = {0.f, 0.f, 0.f, 0.f};
            acc = __builtin_amdgcn_mfma_f32_16x16x32_bf16(a0, b0, acc, 0, 0, 0);
            acc = __builtin_amdgcn_mfma_f32_16x16x32_bf16(a1, b1, acc, 0, 0, 0);
            *(float4*)&out[(size_t)(b * 64 + ncol) * kHW +
                           (size_t)(ty0 + yq) * kW + tx0 + xq] =
                    make_float4(acc[0], acc[1], acc[2], acc[3]);
        }
    }
}

extern "C" void kernel_launch(void* const* d_in, const int* in_sizes, int n_in,
                              void* d_out, int out_size, void* d_ws, size_t ws_size,
                              hipStream_t stream) {
    const float* inp = (const float*)d_in[0];
    const float* Wv  = (const float*)d_in[1];
    const float* bv  = (const float*)d_in[2];
    const float* Wdw = (const float*)d_in[3];
    const float* bdw = (const float*)d_in[4];
    const float* Wom = (const float*)d_in[5];
    const float* bom = (const float*)d_in[6];
    const float* Wo  = (const float*)d_in[7];
    float* outp = (float*)d_out;
    unsigned short* wsu = (unsigned short*)d_ws;
    unsigned short* value = wsu;                      // [b][g][yx][16] bf16
    const unsigned short* Wvh = wsu + kOffWvh / 2;
    const unsigned short* Wvl = wsu + kOffWvl / 2;
    const unsigned short* Wmt = wsu + kOffWom / 2;
    const unsigned short* Wot = wsu + kOffWot / 2;

    k_prep<<<60, 256, 0, stream>>>(Wv, Wom, Wo, wsu);
    k_value<<<kNBv, 256, 0, stream>>>(inp, bv, Wvh, Wvl, value);
    k_main<<<kNT, 256, 0, stream>>>(inp, Wdw, bdw, bom, Wmt, Wot, value, outp);
}